// Round 23
// baseline (215.540 us; speedup 1.0000x reference)
//
#include <hip/hip_runtime.h>
#include <cstdint>
#include <cstddef>

typedef __bf16 bf16_t;
typedef __bf16 bf16x8 __attribute__((ext_vector_type(8)));
typedef float f32x4 __attribute__((ext_vector_type(4)));

#define GLOBAL_AS __attribute__((address_space(1)))
#define LDS_AS    __attribute__((address_space(3)))

__device__ __forceinline__ void glds16(const void* g, void* l) {
    __builtin_amdgcn_global_load_lds((const GLOBAL_AS void*)g, (LDS_AS void*)l, 16, 0, 0);
}

// ---------------- merged prep: conv_x + wcomb + conv2 in ONE launch ----------------
__global__ __launch_bounds__(256) void prep_k(
    const float* __restrict__ x, bf16_t* __restrict__ ha, int n8, int nxb,
    const float* __restrict__ w1, const float* __restrict__ lin_w,
    const float* __restrict__ lin_b, const float* __restrict__ eps_p,
    bf16_t* __restrict__ wc, float* __restrict__ bcomb,
    const float* __restrict__ w2, bf16_t* __restrict__ w2b,
    const float* __restrict__ w3, bf16_t* __restrict__ w3b)
{
    __shared__ float red[256];
    int bid = blockIdx.x, t = threadIdx.x;
    if (bid < nxb) {
        int id = bid * 256 + t;
        if (id >= n8) return;
        const float4* p = (const float4*)x;
        float4 a = p[2 * id], b = p[2 * id + 1];
        bf16x8 o;
        o[0] = (bf16_t)a.x; o[1] = (bf16_t)a.y; o[2] = (bf16_t)a.z; o[3] = (bf16_t)a.w;
        o[4] = (bf16_t)b.x; o[5] = (bf16_t)b.y; o[6] = (bf16_t)b.z; o[7] = (bf16_t)b.w;
        int row = id >> 4, ch = id & 15;
        *(bf16x8*)(ha + (size_t)row * 256 + ch * 8) = o;
    } else if (bid < nxb + 256) {
        int c = bid - nxb;
        const float* w1row = w1 + c * 256;
        float onepe = 1.f + *eps_p;
        float v;
        if (t < 128) {
            float acc = 0.f;
            for (int j = 0; j < 256; j++) acc += w1row[j] * lin_w[j * 128 + t];
            v = acc + onepe * (w1row[t] + w1row[t + 128]);
        } else {
            int m = t - 128;
            v = w1row[m] + w1row[t];
        }
        wc[c * 256 + t] = (bf16_t)v;
        red[t] = w1row[t] * lin_b[t];
        __syncthreads();
        for (int off = 128; off > 0; off >>= 1) {
            if (t < off) red[t] += red[t + off];
            __syncthreads();
        }
        if (t == 0) bcomb[c] = red[0];
    } else {
        int id = (bid - nxb - 256) * 256 + t;
        const float* in; bf16_t* out; int k;
        if (id < 8192) { in = w2; out = w2b; k = id; }
        else if (id < 12288) { in = w3; out = w3b; k = id - 8192; }
        else return;
        const float4* p = (const float4*)in;
        float4 a = p[2 * k], b = p[2 * k + 1];
        bf16x8 o;
        o[0] = (bf16_t)a.x; o[1] = (bf16_t)a.y; o[2] = (bf16_t)a.z; o[3] = (bf16_t)a.w;
        o[4] = (bf16_t)b.x; o[5] = (bf16_t)b.y; o[6] = (bf16_t)b.z; o[7] = (bf16_t)b.w;
        *(bf16x8*)(out + (size_t)k * 8) = o;
    }
}

// ---------------- single-pass bucket sort (bucket = dst>>7, slack 3072/bucket) ----------------
#define CHUNK 8192
#define SLACK 3072

__device__ __forceinline__ int detect_i32(const void* ei, int base, int chunk_n, int t,
                                          int* det) {
    if (t == 0) *det = 0;
    __syncthreads();
    int nchk = chunk_n < 256 ? chunk_n : 256;
    if (t < nchk) {
        unsigned v = ((const unsigned*)ei)[2 * (size_t)(base + t) + 1];
        if (v) atomicOr(det, 1);
    }
    __syncthreads();
    return *det;
}

// per-block multisplit into slack-allocated global buckets
__global__ __launch_bounds__(256) void binfill_k(const void* __restrict__ ei,
                                                 int E, int NBK, int* __restrict__ gcur,
                                                 unsigned* __restrict__ pairs) {
    __shared__ int cnt[1024];
    __shared__ int pref[1024];
    __shared__ int cur[1024];
    __shared__ int gbase[1024];
    __shared__ int red[256];
    __shared__ unsigned slot[CHUNK];
    __shared__ unsigned short sbk[CHUNK];
    __shared__ int det;
    int t = threadIdx.x;
    int base = blockIdx.x * CHUNK;
    int chunk_n = E - base; if (chunk_n > CHUNK) chunk_n = CHUNK;
    for (int b = t; b < 1024; b += 256) cnt[b] = 0;
    int i32 = detect_i32(ei, base, chunk_n, t, &det);   // includes barriers
    // pass 1: local hist
#pragma unroll 4
    for (int i = 0; i < CHUNK / 256; i++) {
        int e = base + t + 256 * i;
        if (e < E) {
            int dst = i32 ? ((const int*)ei)[e] : (int)((const long long*)ei)[e];
            atomicAdd(&cnt[dst >> 7], 1);
        }
    }
    __syncthreads();
    // scan cnt[1024] with 256 threads (4 per thread)
    int t4 = t * 4;
    int c0 = cnt[t4], c1 = cnt[t4 + 1], c2 = cnt[t4 + 2], c3 = cnt[t4 + 3];
    int s = c0 + c1 + c2 + c3;
    red[t] = s;
    __syncthreads();
    for (int off = 1; off < 256; off <<= 1) {
        int add = (t >= off) ? red[t - off] : 0;
        __syncthreads();
        red[t] += add;
        __syncthreads();
    }
    int run = red[t] - s;
    pref[t4] = run; cur[t4] = run; run += c0;
    pref[t4 + 1] = run; cur[t4 + 1] = run; run += c1;
    pref[t4 + 2] = run; cur[t4 + 2] = run; run += c2;
    pref[t4 + 3] = run; cur[t4 + 3] = run;
    __syncthreads();
    // pass 2: place into LDS slots (+ record bucket id)
#pragma unroll 4
    for (int i = 0; i < CHUNK / 256; i++) {
        int e = base + t + 256 * i;
        if (e < E) {
            int dst, src;
            if (i32) { dst = ((const int*)ei)[e]; src = ((const int*)ei)[E + e]; }
            else     { dst = (int)((const long long*)ei)[e]; src = (int)((const long long*)ei)[E + e]; }
            int b = dst >> 7;
            int p = atomicAdd(&cur[b], 1);
            slot[p] = ((unsigned)(dst & 127) << 20) | (unsigned)src;
            sbk[p] = (unsigned short)b;
        }
    }
    __syncthreads();
    // per-bucket global base within the bucket's slack span
    for (int b = t; b < 1024; b += 256) {
        int c = (b + 1 < 1024) ? (pref[b + 1] - pref[b]) : (chunk_n - pref[b]);
        if (b < NBK && c > 0) gbase[b] = b * SLACK + atomicAdd(&gcur[b], c);
    }
    __syncthreads();
    // coalesced flush: direct bucket lookup
    for (int i = t; i < chunk_n; i += 256) {
        int bk = sbk[i];
        pairs[gbase[bk] + (i - pref[bk])] = slot[i];
    }
}

// ---------------- fused level-2 sort + gather: one block per bucket, 1024 threads ----------------
// 16 waves x 8 nodes each; sort phase (hist/scan/placement) is <=3 strided
// iterations per thread; gather uses the R20 measured-best simple loop
// (pairs read twice from L2, 4 rows in flight per 16-lane group).
__global__ __launch_bounds__(1024) void sortgather_k(const unsigned* __restrict__ pairs,
                                                     const int* __restrict__ gcur,
                                                     bf16_t* __restrict__ ha, int N) {
    __shared__ int scnt[128], spref[128], scur[128];
    __shared__ int slsrc[SLACK];
    int t = threadIdx.x;
    int b = blockIdx.x;
    int base = b * SLACK;
    int cntT = gcur[b]; if (cntT > SLACK) cntT = SLACK;
    if (t < 128) scnt[t] = 0;
    __syncthreads();
    for (int i = t; i < cntT; i += 1024)
        atomicAdd(&scnt[pairs[base + i] >> 20], 1);
    __syncthreads();
    if (t < 128) spref[t] = scnt[t];
    __syncthreads();
    for (int off = 1; off < 128; off <<= 1) {
        int v = 0;
        if (t < 128 && t >= off) v = spref[t - off];
        __syncthreads();
        if (t < 128) spref[t] += v;
        __syncthreads();
    }
    if (t < 128) {
        spref[t] -= scnt[t];            // exclusive prefix
        scur[t] = spref[t];
    }
    __syncthreads();
    for (int i = t; i < cntT; i += 1024) {
        unsigned u = pairs[base + i];
        int dl = (int)(u >> 20);
        int p = atomicAdd(&scur[dl], 1);
        slsrc[p] = (int)((u & 0xFFFFFu) << 9);   // byte offset into ha
    }
    __syncthreads();
    // gather: 16 waves x 8 nodes each
    int wv = t >> 6, lane = t & 63;
    int g = lane >> 4, l15 = lane & 15;
#pragma unroll 1
    for (int k = 0; k < 8; k++) {
        int dl = wv * 8 + k;
        int node = b * 128 + dl;
        if (node >= N) break;
        int s = spref[dl], e = s + scnt[dl];
        float acc[8] = {0.f, 0.f, 0.f, 0.f, 0.f, 0.f, 0.f, 0.f};
        for (int i = s + g; i < e; i += 4) {
            int off = slsrc[i];
            bf16x8 v = *(const bf16x8*)((const char*)ha + (size_t)(unsigned)off + l15 * 16);
#pragma unroll
            for (int j = 0; j < 8; j++) acc[j] += (float)v[j];
        }
#pragma unroll
        for (int j = 0; j < 8; j++) {
            acc[j] += __shfl_xor(acc[j], 16);
            acc[j] += __shfl_xor(acc[j], 32);
        }
        if (g == 0) {
            bf16x8 o;
#pragma unroll
            for (int j = 0; j < 8; j++) o[j] = (bf16_t)acc[j];
            *(bf16x8*)(ha + (size_t)node * 256 + 128 + l15 * 8) = o;
        }
    }
}

// ---------------- W-quarter-stationary + A-streamed K=256 MFMA GEMM (v8) ----------------
// R16 structure (W quarter 32KB stationary + A single 32KB glds buffer ->
// 64KB/block, 2 blocks/CU) with BN finalize folded into the prologue.
// Swizzles (both-sides m173): A koff^=(row&7)<<4, W koff^=(col&7)<<4 (2-way=free).
// mfma_f32_16x16x32_bf16 (m89): A lane A[l&15][(l>>4)*8+i]; B lane B[k][l&15];
// D reg i <-> out[row=(l>>4)*4+i][col=l&15].
template<int NCOLTOT, bool BNIN, bool STATS, bool FINAL, bool BIAS>
__global__ __launch_bounds__(512, 4) void gemm_q(
    const bf16_t* __restrict__ A, const bf16_t* __restrict__ W,
    const float* __restrict__ pS, const float* __restrict__ pQ,
    const float* __restrict__ pG, const float* __restrict__ pB, float invN,
    float* __restrict__ sums, float* __restrict__ sqs,
    const float* __restrict__ bias,
    bf16_t* __restrict__ Obf, float* __restrict__ Of, int N, int ntiles, int shift)
{
    __shared__ __align__(16) char smemW[32768];      // 64 cols x 512B, stationary
    __shared__ __align__(16) char smemA[32768];      // 64 rows x 512B, streamed
    __shared__ float2 ssl[BNIN ? 256 : 1];

    const int tid = threadIdx.x;
    const int lane = tid & 63, wid = tid >> 6;
    const int l15 = lane & 15, l4 = lane >> 4;
    const int rowg = wid & 1, colg = wid >> 1;       // 2 rowg x 4 colg
    const int tstride = 1 << shift;
    const int colq = (int)blockIdx.x >> shift;
    const int rb = (int)blockIdx.x & (tstride - 1);

    // stage the W quarter (64 cols) once: swizzled global source, linear LDS
#pragma unroll
    for (int it = 0; it < 4; it++) {
        int d = (it * 512 + tid) * 16;
        int col = d >> 9, koff = d & 511;
        int ksw = koff ^ ((col & 7) << 4);
        glds16((const char*)W + (size_t)(colq * 64 + col) * 512 + ksw, smemW + d);
    }

    // folded finalize: compute BN scale/shift table in LDS
    if constexpr (BNIN) {
        if (tid < 256) {
            float mean = pS[tid] * invN;
            float var = pQ[tid] * invN - mean * mean;
            float s = pG[tid] * rsqrtf(var + 1e-5f);
            ssl[tid] = make_float2(s, pB[tid] - mean * s);
        }
    }

    auto stageA = [&](int t) {
        size_t rowbase = (size_t)t * 64;
#pragma unroll
        for (int it = 0; it < 4; it++) {
            int d = (it * 512 + tid) * 16;
            int row = d >> 9, koff = d & 511;
            int ksw = koff ^ ((row & 7) << 4);
            glds16((const char*)A + (rowbase + row) * 512 + ksw, smemA + d);
        }
    };

    int t = rb;
    if (t < ntiles) stageA(t);
    __syncthreads();                  // W + first A staged; ssl table visible

    // per-thread BN scale/shift for its fixed 4x b128 LDS span (from ssl)
    float2 sslr[32];
    if constexpr (BNIN) {
#pragma unroll
        for (int it = 0; it < 4; it++) {
            int d = (it * 512 + tid) * 16;
            int row = d >> 9;
            int k0 = ((d & 511) ^ ((row & 7) << 4)) >> 1;
#pragma unroll
            for (int i = 0; i < 8; i++) sslr[it * 8 + i] = ssl[k0 + i];
        }
    }

    auto transformA = [&]() {
#pragma unroll
        for (int it = 0; it < 4; it++) {
            int d = (it * 512 + tid) * 16;
            bf16x8 v = *(const bf16x8*)(smemA + d);
            bf16x8 o;
#pragma unroll
            for (int i = 0; i < 8; i++) {
                float2 ss = sslr[it * 8 + i];
                o[i] = (bf16_t)fmaxf((float)v[i] * ss.x + ss.y, 0.f);
            }
            *(bf16x8*)(smemA + d) = o;
        }
    };

    const int colw = colq * 64 + colg * 16 + l15;
    float bbv = 0.f;
    if constexpr (BIAS || FINAL) bbv = bias[colw];
    float sA = 0.f, qA = 0.f;

    f32x4 acc[2];

    auto compute = [&]() {
        acc[0] = f32x4{0.f, 0.f, 0.f, 0.f};
        acc[1] = f32x4{0.f, 0.f, 0.f, 0.f};
        const int col = colg * 16 + l15;
        const int wsw = (col & 7) << 4;
#pragma unroll
        for (int c = 0; c < 8; c++) {
            const int koff = c * 64 + l4 * 16;
            bf16x8 a0, a1;
            {
                int row = rowg * 32 + l15;
                a0 = *(const bf16x8*)(smemA + row * 512 + (koff ^ ((row & 7) << 4)));
                row += 16;
                a1 = *(const bf16x8*)(smemA + row * 512 + (koff ^ ((row & 7) << 4)));
            }
            const bf16x8 b = *(const bf16x8*)(smemW + col * 512 + (koff ^ wsw));
            acc[0] = __builtin_amdgcn_mfma_f32_16x16x32_bf16(a0, b, acc[0], 0, 0, 0);
            acc[1] = __builtin_amdgcn_mfma_f32_16x16x32_bf16(a1, b, acc[1], 0, 0, 0);
        }
    };

    auto epilogue = [&](int t) {
        const int rows0 = t * 64 + rowg * 32;
#pragma unroll
        for (int fr = 0; fr < 2; fr++) {
            int rb0 = rows0 + fr * 16 + l4 * 4;
            f32x4 av = acc[fr];
#pragma unroll
            for (int i = 0; i < 4; i++) {
                int r = rb0 + i;
                if constexpr (FINAL) {
                    if (r < N) Of[(size_t)r * NCOLTOT + colw] = av[i] + bbv;
                } else {
                    float v = av[i];
                    if constexpr (BIAS) v += bbv;
                    bf16_t hv = (bf16_t)v;
                    if (r < N) Obf[(size_t)r * 256 + colw] = hv;
                    if constexpr (STATS) {
                        float vv = (r < N) ? (float)hv : 0.f;
                        sA += vv; qA += vv * vv;
                    }
                }
            }
        }
    };

    if constexpr (BNIN) {
        if (t < ntiles) transformA();
        __syncthreads();
    }

    while (t < ntiles) {
        compute();
        __syncthreads();              // all waves done reading smemA
        int tn = t + tstride;
        if (tn < ntiles) stageA(tn);  // overwrite smemA (safe post-barrier)
        epilogue(t);                  // stores overlap the stage latency
        __syncthreads();              // drain stage; covered by co-resident block
        if constexpr (BNIN) {
            if (tn < ntiles) transformA();
            __syncthreads();          // LDS-only -> cheap drain
        }
        t = tn;
    }

    if constexpr (STATS) {
        sA += __shfl_xor(sA, 16); sA += __shfl_xor(sA, 32);
        qA += __shfl_xor(qA, 16); qA += __shfl_xor(qA, 32);
        if (lane < 16) {
            atomicAdd(&sums[colw], sA);
            atomicAdd(&sqs[colw], qA);
        }
    }
}

extern "C" void kernel_launch(void* const* d_in, const int* in_sizes, int n_in,
                              void* d_out, int out_size, void* d_ws, size_t ws_size,
                              hipStream_t stream)
{
    const int N = in_sizes[0] / 128;
    const int E = in_sizes[1] / 2;
    const float* x     = (const float*)d_in[0];
    const void*  ei    = d_in[1];
    const float* lin_w = (const float*)d_in[2];
    const float* lin_b = (const float*)d_in[3];
    const float* eps   = (const float*)d_in[4];
    const float* w1    = (const float*)d_in[5];
    const float* g1    = (const float*)d_in[6];
    const float* b1    = (const float*)d_in[7];
    const float* w2    = (const float*)d_in[8];
    const float* g2    = (const float*)d_in[9];
    const float* b2    = (const float*)d_in[10];
    const float* w3    = (const float*)d_in[11];
    const float* b3    = (const float*)d_in[12];
    float* out = (float*)d_out;

    char* ws = (char*)d_ws;
    size_t o = 0;
    auto alloc = [&](size_t bytes) -> char* {
        char* p = ws + o;
        o = (o + bytes + 255) & ~(size_t)255;
        return p;
    };
    bf16_t*   ha    = (bf16_t*)alloc((size_t)N * 256 * 2);  // [x | agg], later t2
    bf16_t*   hb    = (bf16_t*)alloc((size_t)N * 256 * 2);  // t1
    bf16_t*   wcb   = (bf16_t*)alloc((size_t)256 * 256 * 2);
    bf16_t*   w2b   = (bf16_t*)alloc((size_t)256 * 256 * 2);
    bf16_t*   w3b   = (bf16_t*)alloc((size_t)128 * 256 * 2);
    float*    bcomb = (float*)alloc(256 * 4);
    float*    stats = (float*)alloc(4 * 256 * 4);   // sum1, sq1, sum2, sq2
    int*      gcur  = (int*)alloc(1024 * 4);
    unsigned* pairs = (unsigned*)alloc((size_t)1024 * SLACK * 4);

    const int NBK = (N + 127) >> 7;
    const float invN = 1.f / (float)N;

    hipMemsetAsync(gcur, 0, 1024 * 4, stream);
    hipMemsetAsync(stats, 0, 4 * 256 * 4, stream);

    // merged prep: conv_x + wcomb + conv2 in one launch
    int nx8 = N * 16;
    int nxb = (nx8 + 255) / 256;
    prep_k<<<nxb + 256 + 48, 256, 0, stream>>>(
        x, ha, nx8, nxb, w1, lin_w, lin_b, eps, wcb, bcomb, w2, w2b, w3, w3b);

    // single-pass bucket sort -> fused level-2 sort + gather
    const int nch = (E + CHUNK - 1) / CHUNK;
    binfill_k<<<nch, 256, 0, stream>>>(ei, E, NBK, gcur, pairs);
    sortgather_k<<<NBK, 1024, 0, stream>>>(pairs, gcur, ha, N);

    const int nt64 = (N + 63) / 64;
    // t1 = [x|agg] @ Wc^T + bcomb (+ BN1 stats): 4 col-quarters x 128 row-strides
    gemm_q<256, false, true, false, true><<<512, 512, 0, stream>>>(
        ha, wcb, nullptr, nullptr, nullptr, nullptr, invN,
        stats + 0, stats + 256, bcomb, hb, nullptr, N, nt64, 7);
    // t2 = relu(BN1(t1))@w2^T (+ BN2 stats); BN1 finalize folded into prologue
    gemm_q<256, true, true, false, false><<<512, 512, 0, stream>>>(
        hb, w2b, stats + 0, stats + 256, g1, b1, invN,
        stats + 512, stats + 768, nullptr, ha, nullptr, N, nt64, 7);
    // out = relu(BN2(t2))@w3^T + b3; BN2 finalize folded into prologue
    gemm_q<128, true, false, true, true><<<512, 512, 0, stream>>>(
        ha, w3b, stats + 512, stats + 768, g2, b2, invN,
        nullptr, nullptr, b3, nullptr, out, N, nt64, 8);
}

// Round 24
// 212.037 us; speedup vs baseline: 1.0165x; 1.0165x over previous
//
#include <hip/hip_runtime.h>
#include <cstdint>
#include <cstddef>

typedef __bf16 bf16_t;
typedef __bf16 bf16x8 __attribute__((ext_vector_type(8)));
typedef float f32x4 __attribute__((ext_vector_type(4)));

#define GLOBAL_AS __attribute__((address_space(1)))
#define LDS_AS    __attribute__((address_space(3)))

__device__ __forceinline__ void glds16(const void* g, void* l) {
    __builtin_amdgcn_global_load_lds((const GLOBAL_AS void*)g, (LDS_AS void*)l, 16, 0, 0);
}

// ---------------- merged prep: conv_x + wcomb + conv2 in ONE launch ----------------
__global__ __launch_bounds__(256) void prep_k(
    const float* __restrict__ x, bf16_t* __restrict__ ha, int n8, int nxb,
    const float* __restrict__ w1, const float* __restrict__ lin_w,
    const float* __restrict__ lin_b, const float* __restrict__ eps_p,
    bf16_t* __restrict__ wc, float* __restrict__ bcomb,
    const float* __restrict__ w2, bf16_t* __restrict__ w2b,
    const float* __restrict__ w3, bf16_t* __restrict__ w3b)
{
    __shared__ float red[256];
    int bid = blockIdx.x, t = threadIdx.x;
    if (bid < nxb) {
        int id = bid * 256 + t;
        if (id >= n8) return;
        const float4* p = (const float4*)x;
        float4 a = p[2 * id], b = p[2 * id + 1];
        bf16x8 o;
        o[0] = (bf16_t)a.x; o[1] = (bf16_t)a.y; o[2] = (bf16_t)a.z; o[3] = (bf16_t)a.w;
        o[4] = (bf16_t)b.x; o[5] = (bf16_t)b.y; o[6] = (bf16_t)b.z; o[7] = (bf16_t)b.w;
        int row = id >> 4, ch = id & 15;
        *(bf16x8*)(ha + (size_t)row * 256 + ch * 8) = o;
    } else if (bid < nxb + 256) {
        int c = bid - nxb;
        const float* w1row = w1 + c * 256;
        float onepe = 1.f + *eps_p;
        float v;
        if (t < 128) {
            float acc = 0.f;
            for (int j = 0; j < 256; j++) acc += w1row[j] * lin_w[j * 128 + t];
            v = acc + onepe * (w1row[t] + w1row[t + 128]);
        } else {
            int m = t - 128;
            v = w1row[m] + w1row[t];
        }
        wc[c * 256 + t] = (bf16_t)v;
        red[t] = w1row[t] * lin_b[t];
        __syncthreads();
        for (int off = 128; off > 0; off >>= 1) {
            if (t < off) red[t] += red[t + off];
            __syncthreads();
        }
        if (t == 0) bcomb[c] = red[0];
    } else {
        int id = (bid - nxb - 256) * 256 + t;
        const float* in; bf16_t* out; int k;
        if (id < 8192) { in = w2; out = w2b; k = id; }
        else if (id < 12288) { in = w3; out = w3b; k = id - 8192; }
        else return;
        const float4* p = (const float4*)in;
        float4 a = p[2 * k], b = p[2 * k + 1];
        bf16x8 o;
        o[0] = (bf16_t)a.x; o[1] = (bf16_t)a.y; o[2] = (bf16_t)a.z; o[3] = (bf16_t)a.w;
        o[4] = (bf16_t)b.x; o[5] = (bf16_t)b.y; o[6] = (bf16_t)b.z; o[7] = (bf16_t)b.w;
        *(bf16x8*)(out + (size_t)k * 8) = o;
    }
}

// ---------------- single-pass bucket sort (bucket = dst>>7, slack 3072/bucket) ----------------
#define CHUNK 8192
#define SLACK 3072

__device__ __forceinline__ int detect_i32(const void* ei, int base, int chunk_n, int t,
                                          int* det) {
    if (t == 0) *det = 0;
    __syncthreads();
    int nchk = chunk_n < 256 ? chunk_n : 256;
    if (t < nchk) {
        unsigned v = ((const unsigned*)ei)[2 * (size_t)(base + t) + 1];
        if (v) atomicOr(det, 1);
    }
    __syncthreads();
    return *det;
}

// per-block multisplit into slack-allocated global buckets
__global__ __launch_bounds__(256) void binfill_k(const void* __restrict__ ei,
                                                 int E, int NBK, int* __restrict__ gcur,
                                                 unsigned* __restrict__ pairs) {
    __shared__ int cnt[1024];
    __shared__ int pref[1024];
    __shared__ int cur[1024];
    __shared__ int gbase[1024];
    __shared__ int red[256];
    __shared__ unsigned slot[CHUNK];
    __shared__ unsigned short sbk[CHUNK];
    __shared__ int det;
    int t = threadIdx.x;
    int base = blockIdx.x * CHUNK;
    int chunk_n = E - base; if (chunk_n > CHUNK) chunk_n = CHUNK;
    for (int b = t; b < 1024; b += 256) cnt[b] = 0;
    int i32 = detect_i32(ei, base, chunk_n, t, &det);   // includes barriers
    // pass 1: local hist
#pragma unroll 4
    for (int i = 0; i < CHUNK / 256; i++) {
        int e = base + t + 256 * i;
        if (e < E) {
            int dst = i32 ? ((const int*)ei)[e] : (int)((const long long*)ei)[e];
            atomicAdd(&cnt[dst >> 7], 1);
        }
    }
    __syncthreads();
    // scan cnt[1024] with 256 threads (4 per thread)
    int t4 = t * 4;
    int c0 = cnt[t4], c1 = cnt[t4 + 1], c2 = cnt[t4 + 2], c3 = cnt[t4 + 3];
    int s = c0 + c1 + c2 + c3;
    red[t] = s;
    __syncthreads();
    for (int off = 1; off < 256; off <<= 1) {
        int add = (t >= off) ? red[t - off] : 0;
        __syncthreads();
        red[t] += add;
        __syncthreads();
    }
    int run = red[t] - s;
    pref[t4] = run; cur[t4] = run; run += c0;
    pref[t4 + 1] = run; cur[t4 + 1] = run; run += c1;
    pref[t4 + 2] = run; cur[t4 + 2] = run; run += c2;
    pref[t4 + 3] = run; cur[t4 + 3] = run;
    __syncthreads();
    // pass 2: place into LDS slots (+ record bucket id)
#pragma unroll 4
    for (int i = 0; i < CHUNK / 256; i++) {
        int e = base + t + 256 * i;
        if (e < E) {
            int dst, src;
            if (i32) { dst = ((const int*)ei)[e]; src = ((const int*)ei)[E + e]; }
            else     { dst = (int)((const long long*)ei)[e]; src = (int)((const long long*)ei)[E + e]; }
            int b = dst >> 7;
            int p = atomicAdd(&cur[b], 1);
            slot[p] = ((unsigned)(dst & 127) << 20) | (unsigned)src;
            sbk[p] = (unsigned short)b;
        }
    }
    __syncthreads();
    // per-bucket global base within the bucket's slack span
    for (int b = t; b < 1024; b += 256) {
        int c = (b + 1 < 1024) ? (pref[b + 1] - pref[b]) : (chunk_n - pref[b]);
        if (b < NBK && c > 0) gbase[b] = b * SLACK + atomicAdd(&gcur[b], c);
    }
    __syncthreads();
    // coalesced flush: direct bucket lookup
    for (int i = t; i < chunk_n; i += 256) {
        int bk = sbk[i];
        pairs[gbase[bk] + (i - pref[bk])] = slot[i];
    }
}

// ---------------- fused level-2 sort + gather: one block per bucket (R20 form) ----------------
// 512 threads; sort phase from global pairs (L2-resident, read twice);
// 8 waves gather 16 nodes each, 4 rows in flight per 16-lane group.
__global__ __launch_bounds__(512) void sortgather_k(const unsigned* __restrict__ pairs,
                                                    const int* __restrict__ gcur,
                                                    bf16_t* __restrict__ ha, int N) {
    __shared__ int scnt[128], spref[128], scur[128];
    __shared__ int slsrc[SLACK];
    int t = threadIdx.x;
    int b = blockIdx.x;
    int base = b * SLACK;
    int cntT = gcur[b]; if (cntT > SLACK) cntT = SLACK;
    if (t < 128) scnt[t] = 0;
    __syncthreads();
    for (int i = t; i < cntT; i += 512)
        atomicAdd(&scnt[pairs[base + i] >> 20], 1);
    __syncthreads();
    if (t < 128) spref[t] = scnt[t];
    __syncthreads();
    for (int off = 1; off < 128; off <<= 1) {
        int v = 0;
        if (t < 128 && t >= off) v = spref[t - off];
        __syncthreads();
        if (t < 128) spref[t] += v;
        __syncthreads();
    }
    if (t < 128) {
        spref[t] -= scnt[t];            // exclusive prefix
        scur[t] = spref[t];
    }
    __syncthreads();
    for (int i = t; i < cntT; i += 512) {
        unsigned u = pairs[base + i];
        int dl = (int)(u >> 20);
        int p = atomicAdd(&scur[dl], 1);
        slsrc[p] = (int)((u & 0xFFFFFu) << 9);   // byte offset into ha
    }
    __syncthreads();
    // gather: 8 waves x 16 nodes each
    int wv = t >> 6, lane = t & 63;
    int g = lane >> 4, l15 = lane & 15;
#pragma unroll 1
    for (int k = 0; k < 16; k++) {
        int dl = wv * 16 + k;
        int node = b * 128 + dl;
        if (node >= N) break;
        int s = spref[dl], e = s + scnt[dl];
        float acc[8] = {0.f, 0.f, 0.f, 0.f, 0.f, 0.f, 0.f, 0.f};
        for (int i = s + g; i < e; i += 4) {
            int off = slsrc[i];
            bf16x8 v = *(const bf16x8*)((const char*)ha + (size_t)(unsigned)off + l15 * 16);
#pragma unroll
            for (int j = 0; j < 8; j++) acc[j] += (float)v[j];
        }
#pragma unroll
        for (int j = 0; j < 8; j++) {
            acc[j] += __shfl_xor(acc[j], 16);
            acc[j] += __shfl_xor(acc[j], 32);
        }
        if (g == 0) {
            bf16x8 o;
#pragma unroll
            for (int j = 0; j < 8; j++) o[j] = (bf16_t)acc[j];
            *(bf16x8*)(ha + (size_t)node * 256 + 128 + l15 * 8) = o;
        }
    }
}

// ---------------- W-quarter-stationary + A-streamed K=256 MFMA GEMM (v8) ----------------
// R16 structure (W quarter 32KB stationary + A single 32KB glds buffer ->
// 64KB/block, 2 blocks/CU) with BN finalize folded into the prologue.
// Swizzles (both-sides m173): A koff^=(row&7)<<4, W koff^=(col&7)<<4 (2-way=free).
// mfma_f32_16x16x32_bf16 (m89): A lane A[l&15][(l>>4)*8+i]; B lane B[k][l&15];
// D reg i <-> out[row=(l>>4)*4+i][col=l&15].
template<int NCOLTOT, bool BNIN, bool STATS, bool FINAL, bool BIAS>
__global__ __launch_bounds__(512, 4) void gemm_q(
    const bf16_t* __restrict__ A, const bf16_t* __restrict__ W,
    const float* __restrict__ pS, const float* __restrict__ pQ,
    const float* __restrict__ pG, const float* __restrict__ pB, float invN,
    float* __restrict__ sums, float* __restrict__ sqs,
    const float* __restrict__ bias,
    bf16_t* __restrict__ Obf, float* __restrict__ Of, int N, int ntiles, int shift)
{
    __shared__ __align__(16) char smemW[32768];      // 64 cols x 512B, stationary
    __shared__ __align__(16) char smemA[32768];      // 64 rows x 512B, streamed
    __shared__ float2 ssl[BNIN ? 256 : 1];

    const int tid = threadIdx.x;
    const int lane = tid & 63, wid = tid >> 6;
    const int l15 = lane & 15, l4 = lane >> 4;
    const int rowg = wid & 1, colg = wid >> 1;       // 2 rowg x 4 colg
    const int tstride = 1 << shift;
    const int colq = (int)blockIdx.x >> shift;
    const int rb = (int)blockIdx.x & (tstride - 1);

    // stage the W quarter (64 cols) once: swizzled global source, linear LDS
#pragma unroll
    for (int it = 0; it < 4; it++) {
        int d = (it * 512 + tid) * 16;
        int col = d >> 9, koff = d & 511;
        int ksw = koff ^ ((col & 7) << 4);
        glds16((const char*)W + (size_t)(colq * 64 + col) * 512 + ksw, smemW + d);
    }

    // folded finalize: compute BN scale/shift table in LDS
    if constexpr (BNIN) {
        if (tid < 256) {
            float mean = pS[tid] * invN;
            float var = pQ[tid] * invN - mean * mean;
            float s = pG[tid] * rsqrtf(var + 1e-5f);
            ssl[tid] = make_float2(s, pB[tid] - mean * s);
        }
    }

    auto stageA = [&](int t) {
        size_t rowbase = (size_t)t * 64;
#pragma unroll
        for (int it = 0; it < 4; it++) {
            int d = (it * 512 + tid) * 16;
            int row = d >> 9, koff = d & 511;
            int ksw = koff ^ ((row & 7) << 4);
            glds16((const char*)A + (rowbase + row) * 512 + ksw, smemA + d);
        }
    };

    int t = rb;
    if (t < ntiles) stageA(t);
    __syncthreads();                  // W + first A staged; ssl table visible

    // per-thread BN scale/shift for its fixed 4x b128 LDS span (from ssl)
    float2 sslr[32];
    if constexpr (BNIN) {
#pragma unroll
        for (int it = 0; it < 4; it++) {
            int d = (it * 512 + tid) * 16;
            int row = d >> 9;
            int k0 = ((d & 511) ^ ((row & 7) << 4)) >> 1;
#pragma unroll
            for (int i = 0; i < 8; i++) sslr[it * 8 + i] = ssl[k0 + i];
        }
    }

    auto transformA = [&]() {
#pragma unroll
        for (int it = 0; it < 4; it++) {
            int d = (it * 512 + tid) * 16;
            bf16x8 v = *(const bf16x8*)(smemA + d);
            bf16x8 o;
#pragma unroll
            for (int i = 0; i < 8; i++) {
                float2 ss = sslr[it * 8 + i];
                o[i] = (bf16_t)fmaxf((float)v[i] * ss.x + ss.y, 0.f);
            }
            *(bf16x8*)(smemA + d) = o;
        }
    };

    const int colw = colq * 64 + colg * 16 + l15;
    float bbv = 0.f;
    if constexpr (BIAS || FINAL) bbv = bias[colw];
    float sA = 0.f, qA = 0.f;

    f32x4 acc[2];

    auto compute = [&]() {
        acc[0] = f32x4{0.f, 0.f, 0.f, 0.f};
        acc[1] = f32x4{0.f, 0.f, 0.f, 0.f};
        const int col = colg * 16 + l15;
        const int wsw = (col & 7) << 4;
#pragma unroll
        for (int c = 0; c < 8; c++) {
            const int koff = c * 64 + l4 * 16;
            bf16x8 a0, a1;
            {
                int row = rowg * 32 + l15;
                a0 = *(const bf16x8*)(smemA + row * 512 + (koff ^ ((row & 7) << 4)));
                row += 16;
                a1 = *(const bf16x8*)(smemA + row * 512 + (koff ^ ((row & 7) << 4)));
            }
            const bf16x8 b = *(const bf16x8*)(smemW + col * 512 + (koff ^ wsw));
            acc[0] = __builtin_amdgcn_mfma_f32_16x16x32_bf16(a0, b, acc[0], 0, 0, 0);
            acc[1] = __builtin_amdgcn_mfma_f32_16x16x32_bf16(a1, b, acc[1], 0, 0, 0);
        }
    };

    auto epilogue = [&](int t) {
        const int rows0 = t * 64 + rowg * 32;
#pragma unroll
        for (int fr = 0; fr < 2; fr++) {
            int rb0 = rows0 + fr * 16 + l4 * 4;
            f32x4 av = acc[fr];
#pragma unroll
            for (int i = 0; i < 4; i++) {
                int r = rb0 + i;
                if constexpr (FINAL) {
                    if (r < N) Of[(size_t)r * NCOLTOT + colw] = av[i] + bbv;
                } else {
                    float v = av[i];
                    if constexpr (BIAS) v += bbv;
                    bf16_t hv = (bf16_t)v;
                    if (r < N) Obf[(size_t)r * 256 + colw] = hv;
                    if constexpr (STATS) {
                        float vv = (r < N) ? (float)hv : 0.f;
                        sA += vv; qA += vv * vv;
                    }
                }
            }
        }
    };

    if constexpr (BNIN) {
        if (t < ntiles) transformA();
        __syncthreads();
    }

    while (t < ntiles) {
        compute();
        __syncthreads();              // all waves done reading smemA
        int tn = t + tstride;
        if (tn < ntiles) stageA(tn);  // overwrite smemA (safe post-barrier)
        epilogue(t);                  // stores overlap the stage latency
        __syncthreads();              // drain stage; covered by co-resident block
        if constexpr (BNIN) {
            if (tn < ntiles) transformA();
            __syncthreads();          // LDS-only -> cheap drain
        }
        t = tn;
    }

    if constexpr (STATS) {
        sA += __shfl_xor(sA, 16); sA += __shfl_xor(sA, 32);
        qA += __shfl_xor(qA, 16); qA += __shfl_xor(qA, 32);
        if (lane < 16) {
            atomicAdd(&sums[colw], sA);
            atomicAdd(&sqs[colw], qA);
        }
    }
}

extern "C" void kernel_launch(void* const* d_in, const int* in_sizes, int n_in,
                              void* d_out, int out_size, void* d_ws, size_t ws_size,
                              hipStream_t stream)
{
    const int N = in_sizes[0] / 128;
    const int E = in_sizes[1] / 2;
    const float* x     = (const float*)d_in[0];
    const void*  ei    = d_in[1];
    const float* lin_w = (const float*)d_in[2];
    const float* lin_b = (const float*)d_in[3];
    const float* eps   = (const float*)d_in[4];
    const float* w1    = (const float*)d_in[5];
    const float* g1    = (const float*)d_in[6];
    const float* b1    = (const float*)d_in[7];
    const float* w2    = (const float*)d_in[8];
    const float* g2    = (const float*)d_in[9];
    const float* b2    = (const float*)d_in[10];
    const float* w3    = (const float*)d_in[11];
    const float* b3    = (const float*)d_in[12];
    float* out = (float*)d_out;

    char* ws = (char*)d_ws;
    size_t o = 0;
    auto alloc = [&](size_t bytes) -> char* {
        char* p = ws + o;
        o = (o + bytes + 255) & ~(size_t)255;
        return p;
    };
    bf16_t*   ha    = (bf16_t*)alloc((size_t)N * 256 * 2);  // [x | agg], later t2
    bf16_t*   hb    = (bf16_t*)alloc((size_t)N * 256 * 2);  // t1
    bf16_t*   wcb   = (bf16_t*)alloc((size_t)256 * 256 * 2);
    bf16_t*   w2b   = (bf16_t*)alloc((size_t)256 * 256 * 2);
    bf16_t*   w3b   = (bf16_t*)alloc((size_t)128 * 256 * 2);
    float*    bcomb = (float*)alloc(256 * 4);
    float*    stats = (float*)alloc(4 * 256 * 4);   // sum1, sq1, sum2, sq2
    int*      gcur  = (int*)alloc(1024 * 4);
    unsigned* pairs = (unsigned*)alloc((size_t)1024 * SLACK * 4);

    const int NBK = (N + 127) >> 7;
    const float invN = 1.f / (float)N;

    hipMemsetAsync(gcur, 0, 1024 * 4, stream);
    hipMemsetAsync(stats, 0, 4 * 256 * 4, stream);

    // merged prep: conv_x + wcomb + conv2 in one launch
    int nx8 = N * 16;
    int nxb = (nx8 + 255) / 256;
    prep_k<<<nxb + 256 + 48, 256, 0, stream>>>(
        x, ha, nx8, nxb, w1, lin_w, lin_b, eps, wcb, bcomb, w2, w2b, w3, w3b);

    // single-pass bucket sort -> fused level-2 sort + gather
    const int nch = (E + CHUNK - 1) / CHUNK;
    binfill_k<<<nch, 256, 0, stream>>>(ei, E, NBK, gcur, pairs);
    sortgather_k<<<NBK, 512, 0, stream>>>(pairs, gcur, ha, N);

    const int nt64 = (N + 63) / 64;
    // t1 = [x|agg] @ Wc^T + bcomb (+ BN1 stats): 4 col-quarters x 128 row-strides
    gemm_q<256, false, true, false, true><<<512, 512, 0, stream>>>(
        ha, wcb, nullptr, nullptr, nullptr, nullptr, invN,
        stats + 0, stats + 256, bcomb, hb, nullptr, N, nt64, 7);
    // t2 = relu(BN1(t1))@w2^T (+ BN2 stats); BN1 finalize folded into prologue
    gemm_q<256, true, true, false, false><<<512, 512, 0, stream>>>(
        hb, w2b, stats + 0, stats + 256, g1, b1, invN,
        stats + 512, stats + 768, nullptr, ha, nullptr, N, nt64, 7);
    // out = relu(BN2(t2))@w3^T + b3; BN2 finalize folded into prologue
    gemm_q<128, true, false, true, true><<<512, 512, 0, stream>>>(
        ha, w3b, stats + 512, stats + 768, g2, b2, invN,
        nullptr, nullptr, b3, nullptr, out, N, nt64, 8);
}